// Round 1
// baseline (149.116 us; speedup 1.0000x reference)
//
#include <hip/hip_runtime.h>
#include <hip/hip_bf16.h>

typedef __attribute__((ext_vector_type(8))) short bf16x8;
typedef __attribute__((ext_vector_type(4))) float f32x4;

#define U_LD 2176      // padded K (multiple of 64)
#define K_REAL 2145    // 33*65
#define NKT 34         // 2176/64
#define DIM0 33
#define DIM1 33
#define DIM2 65
#define NROW 2048
#define OO 128

__device__ __forceinline__ unsigned short f2bf(float f) {
  union { float f; unsigned u; } v; v.f = f;
  unsigned r = v.u + 0x7fffu + ((v.u >> 16) & 1u);   // round-to-nearest-even
  return (unsigned short)(r >> 16);
}

#define GLOAD_LDS16(SRC, DST) \
  __builtin_amdgcn_global_load_lds((const __attribute__((address_space(1))) void*)(SRC), \
                                   (__attribute__((address_space(3))) void*)(DST), 16, 0, 0)

// ---- U[n][k] = bf16( x1[n,b] * x2[n,c] ),  k = b*65+c, zero-padded to 2176 ----
__global__ __launch_bounds__(256) void prep_u_kernel(const float* __restrict__ x1,
                                                     const float* __restrict__ x2,
                                                     ushort* __restrict__ U) {
  __shared__ float s1[DIM1], s2[DIM2];
  int n = blockIdx.x;
  int tid = threadIdx.x;
  if (tid < DIM1) s1[tid] = x1[n * DIM1 + tid];
  int t2 = tid - DIM1;
  if (t2 >= 0 && t2 < DIM2) s2[t2] = x2[n * DIM2 + t2];
  __syncthreads();
  for (int k8 = tid; k8 < U_LD / 8; k8 += 256) {
    union { ushort us[8]; uint4 v; } pk;
#pragma unroll
    for (int j = 0; j < 8; ++j) {
      int k = k8 * 8 + j;
      float val = 0.f;
      if (k < K_REAL) { int b = k / DIM2; int c = k - b * DIM2; val = s1[b] * s2[c]; }
      pk.us[j] = f2bf(val);
    }
    *(uint4*)&U[(size_t)n * U_LD + k8 * 8] = pk.v;
  }
}

// ---- Wt[a][o][k] = bf16( W[a,b,c,o] ), k = b*65+c, zero-padded ----
__global__ __launch_bounds__(256) void prep_wt_kernel(const float* __restrict__ W,
                                                      ushort* __restrict__ Wt) {
  int o = threadIdx.x;                     // 0..127
  int k8 = blockIdx.x * 2 + threadIdx.y;   // 0..271
  int a = blockIdx.y;                      // 0..32
  union { ushort us[8]; uint4 v; } pk;
#pragma unroll
  for (int j = 0; j < 8; ++j) {
    int k = k8 * 8 + j;
    float val = 0.f;
    if (k < K_REAL) {
      int b = k / DIM2; int c = k - b * DIM2;
      val = W[(((size_t)a * DIM1 + b) * DIM2 + c) * OO + o];
    }
    pk.us[j] = f2bf(val);
  }
  *(uint4*)&Wt[((size_t)a * OO + o) * U_LD + k8 * 8] = pk.v;
}

// ---- main GEMM: per block (m-tile of 128 rows, one a): P = U_tile x Wt_a,
//      epilogue: out[n,o] += x0[n,a] * P[n,o]  (atomic) ----
__global__ __launch_bounds__(256) void gemm_kernel(const ushort* __restrict__ U,
                                                   const ushort* __restrict__ Wt,
                                                   const float* __restrict__ x0,
                                                   float* __restrict__ out) {
  // A region: [128 rows][64 k] bf16 = 16KB (ushort idx 0..8191)
  // B region: [128 o  ][64 k] bf16 = 16KB (ushort idx 8192..16383)
  __shared__ ushort lds[16384];

  int tid = threadIdx.x;
  int lane = tid & 63;
  int w = tid >> 6;
  int wr = w >> 1, wc = w & 1;

  // XCD-aware bijective swizzle: 528 blocks, 528/8 = 66 per XCD.
  int orig = (int)blockIdx.x;
  int logical = (orig & 7) * 66 + (orig >> 3);
  int a = logical >> 4;        // 0..32  (a-major => consecutive logical share Wt_a in L2)
  int m = logical & 15;        // 0..15
  int n0 = m * 128;

  int kblk = lane >> 4;        // 0..3
  int r15 = lane & 15;
  int swz = lane & 7;          // == row&7 for all fragment rows this lane touches

  f32x4 acc[4][4];
#pragma unroll
  for (int mi = 0; mi < 4; ++mi)
#pragma unroll
    for (int ni = 0; ni < 4; ++ni)
      acc[mi][ni] = (f32x4){0.f, 0.f, 0.f, 0.f};

  const ushort* WtA = Wt + (size_t)a * OO * U_LD;

  for (int t = 0; t < NKT; ++t) {
    int kk = t * 64;
    // stage A: 1024 chunks of 16B; chunk c -> LDS byte c*16 (linear dest),
    // source slot = slot ^ (row&7)  (involution; undone on the read side)
#pragma unroll
    for (int i = 0; i < 4; ++i) {
      int c = i * 256 + tid;
      int row = c >> 3;
      int ss = (c & 7) ^ (row & 7);
      const ushort* src = U + (size_t)(n0 + row) * U_LD + kk + ss * 8;
      GLOAD_LDS16(src, &lds[(size_t)c * 8]);
    }
    // stage B
#pragma unroll
    for (int i = 0; i < 4; ++i) {
      int c = i * 256 + tid;
      int row = c >> 3;                       // o index
      int ss = (c & 7) ^ (row & 7);
      const ushort* src = WtA + (size_t)row * U_LD + kk + ss * 8;
      GLOAD_LDS16(src, &lds[8192 + (size_t)c * 8]);
    }
    __syncthreads();   // compiler drains vmcnt(0) -> LDS tile ready for all waves

#pragma unroll
    for (int ks = 0; ks < 2; ++ks) {
      bf16x8 af[4], bfr[4];
#pragma unroll
      for (int mi = 0; mi < 4; ++mi) {
        int off = (wr * 64 + mi * 16 + r15) * 128 + ((((ks * 4) + kblk) ^ swz) << 4);
        af[mi] = *(const bf16x8*)((const char*)lds + off);
      }
#pragma unroll
      for (int ni = 0; ni < 4; ++ni) {
        int off = 16384 + (wc * 64 + ni * 16 + r15) * 128 + ((((ks * 4) + kblk) ^ swz) << 4);
        bfr[ni] = *(const bf16x8*)((const char*)lds + off);
      }
#pragma unroll
      for (int mi = 0; mi < 4; ++mi)
#pragma unroll
        for (int ni = 0; ni < 4; ++ni)
          acc[mi][ni] = __builtin_amdgcn_mfma_f32_16x16x32_bf16(af[mi], bfr[ni], acc[mi][ni], 0, 0, 0);
    }
    __syncthreads();   // all waves done reading before next stage overwrites
  }

  // epilogue: scale by x0[row, a], atomic-accumulate into out
  int jrow = (lane >> 4) * 4;
#pragma unroll
  for (int mi = 0; mi < 4; ++mi) {
#pragma unroll
    for (int j = 0; j < 4; ++j) {
      int row = n0 + wr * 64 + mi * 16 + jrow + j;
      float s = x0[(size_t)row * DIM0 + a];
#pragma unroll
      for (int ni = 0; ni < 4; ++ni) {
        int col = wc * 64 + ni * 16 + r15;
        atomicAdd(&out[(size_t)row * OO + col], acc[mi][ni][j] * s);
      }
    }
  }
}

// ---- bias + relu, in place on d_out ----
__global__ __launch_bounds__(256) void relu_kernel(float* __restrict__ out,
                                                   const float* __restrict__ bias) {
  int i = blockIdx.x * 256 + threadIdx.x;
  out[i] = fmaxf(out[i] + bias[i & (OO - 1)], 0.f);
}

extern "C" void kernel_launch(void* const* d_in, const int* in_sizes, int n_in,
                              void* d_out, int out_size, void* d_ws, size_t ws_size,
                              hipStream_t stream) {
  const float* x0   = (const float*)d_in[0];
  const float* x1   = (const float*)d_in[1];
  const float* x2   = (const float*)d_in[2];
  const float* W    = (const float*)d_in[3];
  const float* bias = (const float*)d_in[4];
  float* out = (float*)d_out;

  ushort* U  = (ushort*)d_ws;                                   // 2048*2176*2 = 8,912,896 B
  ushort* Wt = (ushort*)((char*)d_ws + (size_t)8912896);        // 33*128*2176*2 = 18,382,848 B

  hipMemsetAsync(d_out, 0, (size_t)NROW * OO * sizeof(float), stream);
  prep_u_kernel<<<NROW, 256, 0, stream>>>(x1, x2, U);
  prep_wt_kernel<<<dim3(136, 33), dim3(128, 2), 0, stream>>>(W, Wt);
  gemm_kernel<<<528, 256, 0, stream>>>(U, Wt, x0, out);
  relu_kernel<<<(NROW * OO) / 256, 256, 0, stream>>>(out, bias);
}

// Round 2
// 119.870 us; speedup vs baseline: 1.2440x; 1.2440x over previous
//
#include <hip/hip_runtime.h>
#include <hip/hip_bf16.h>

typedef __attribute__((ext_vector_type(8))) short bf16x8;
typedef __attribute__((ext_vector_type(4))) float f32x4;

#define U_LD 2176      // padded K (multiple of 64)
#define K_REAL 2145    // 33*65
#define NKT 34         // 2176/64
#define DIM0 33
#define DIM1 33
#define DIM2 65
#define NROW 2048
#define OO 128

__device__ __forceinline__ unsigned short f2bf(float f) {
  union { float f; unsigned u; } v; v.f = f;
  unsigned r = v.u + 0x7fffu + ((v.u >> 16) & 1u);   // round-to-nearest-even
  return (unsigned short)(r >> 16);
}

#define GLOAD_LDS16(SRC, DST) \
  __builtin_amdgcn_global_load_lds((const __attribute__((address_space(1))) void*)(SRC), \
                                   (__attribute__((address_space(3))) void*)(DST), 16, 0, 0)

// ---- U[n][k] = bf16( x1[n,b] * x2[n,c] ),  k = b*65+c, zero-padded to 2176 ----
__global__ __launch_bounds__(256) void prep_u_kernel(const float* __restrict__ x1,
                                                     const float* __restrict__ x2,
                                                     ushort* __restrict__ U) {
  __shared__ float s1[DIM1], s2[DIM2];
  int n = blockIdx.x;
  int tid = threadIdx.x;
  if (tid < DIM1) s1[tid] = x1[n * DIM1 + tid];
  int t2 = tid - DIM1;
  if (t2 >= 0 && t2 < DIM2) s2[t2] = x2[n * DIM2 + t2];
  __syncthreads();
  for (int k8 = tid; k8 < U_LD / 8; k8 += 256) {
    union { ushort us[8]; uint4 v; } pk;
#pragma unroll
    for (int j = 0; j < 8; ++j) {
      int k = k8 * 8 + j;
      float val = 0.f;
      if (k < K_REAL) { int b = k / DIM2; int c = k - b * DIM2; val = s1[b] * s2[c]; }
      pk.us[j] = f2bf(val);
    }
    *(uint4*)&U[(size_t)n * U_LD + k8 * 8] = pk.v;
  }
}

// ---- Wt[a][o][k] = bf16( W[a,b,c,o] ), k = b*65+c, zero-padded ----
// LDS transpose: coalesced f32 reads (o-contiguous), 128B-segment bf16 writes (k-contiguous)
__global__ __launch_bounds__(256) void prep_wt_kernel(const float* __restrict__ W,
                                                      ushort* __restrict__ Wt) {
  __shared__ ushort s[64][130];   // [k][o], pad to 130 to spread banks
  int a = blockIdx.y;
  int k0 = blockIdx.x * 64;       // 34 slabs of 64 k
  int tid = threadIdx.x;
  for (int idx = tid; idx < 64 * 32; idx += 256) {
    int kk = idx >> 5;
    int og = (idx & 31) * 4;
    int k = k0 + kk;
    float4 v = make_float4(0.f, 0.f, 0.f, 0.f);
    if (k < K_REAL) {
      int b = k / DIM2; int c = k - b * DIM2;
      v = *(const float4*)&W[(((size_t)a * DIM1 + b) * DIM2 + c) * OO + og];
    }
    s[kk][og]     = f2bf(v.x);
    s[kk][og + 1] = f2bf(v.y);
    s[kk][og + 2] = f2bf(v.z);
    s[kk][og + 3] = f2bf(v.w);
  }
  __syncthreads();
  int o  = tid >> 1;
  int kh = (tid & 1) * 32;
  union { ushort us[32]; uint4 v[4]; } pk;
#pragma unroll
  for (int j = 0; j < 32; ++j) pk.us[j] = s[kh + j][o];
  uint4* dst = (uint4*)&Wt[((size_t)a * OO + o) * U_LD + k0 + kh];
#pragma unroll
  for (int q = 0; q < 4; ++q) dst[q] = pk.v[q];
}

// ---- main GEMM: per block (m-tile of 64 rows, one a): P = U_tile x Wt_a,
//      epilogue: out[n,o] += x0[n,a] * P[n,o]  (atomic) ----
// 64x128 tile, 4 waves (2 row-halves x 2 col-halves), 1056 blocks -> ~4 blocks/CU
__global__ __launch_bounds__(256) void gemm_kernel(const ushort* __restrict__ U,
                                                   const ushort* __restrict__ Wt,
                                                   const float* __restrict__ x0,
                                                   float* __restrict__ out) {
  // A region: [64 rows][64 k] bf16 = 8KB (ushort 0..4095)
  // B region: [128 o ][64 k] bf16 = 16KB (ushort 4096..12287)
  __shared__ ushort lds[12288];

  int tid = threadIdx.x;
  int lane = tid & 63;
  int w = tid >> 6;
  int wr = w >> 1, wc = w & 1;

  // XCD-aware bijective swizzle: 1056 blocks, 1056/8 = 132 per XCD.
  int orig = (int)blockIdx.x;
  int logical = (orig & 7) * 132 + (orig >> 3);
  int a = logical >> 5;        // 0..32 (a-major: consecutive logical share Wt_a in L2)
  int m = logical & 31;        // 0..31
  int n0 = m * 64;

  int kblk = lane >> 4;        // 0..3
  int r15 = lane & 15;
  int swz = lane & 7;          // == row&7 for all fragment rows this lane touches

  f32x4 acc[2][4];
#pragma unroll
  for (int mi = 0; mi < 2; ++mi)
#pragma unroll
    for (int ni = 0; ni < 4; ++ni)
      acc[mi][ni] = (f32x4){0.f, 0.f, 0.f, 0.f};

  const ushort* WtA = Wt + (size_t)a * OO * U_LD;

  for (int t = 0; t < NKT; ++t) {
    int kk = t * 64;
    // stage A: 512 chunks of 16B; linear LDS dest, inverse-swizzled global source
#pragma unroll
    for (int i = 0; i < 2; ++i) {
      int c = i * 256 + tid;
      int row = c >> 3;
      int ss = (c & 7) ^ (row & 7);
      const ushort* src = U + (size_t)(n0 + row) * U_LD + kk + ss * 8;
      GLOAD_LDS16(src, &lds[(size_t)c * 8]);
    }
    // stage B: 1024 chunks
#pragma unroll
    for (int i = 0; i < 4; ++i) {
      int c = i * 256 + tid;
      int row = c >> 3;                       // o index
      int ss = (c & 7) ^ (row & 7);
      const ushort* src = WtA + (size_t)row * U_LD + kk + ss * 8;
      GLOAD_LDS16(src, &lds[4096 + (size_t)c * 8]);
    }
    __syncthreads();

#pragma unroll
    for (int ks = 0; ks < 2; ++ks) {
      bf16x8 af[2], bfr[4];
#pragma unroll
      for (int mi = 0; mi < 2; ++mi) {
        int off = (wr * 32 + mi * 16 + r15) * 128 + ((((ks * 4) + kblk) ^ swz) << 4);
        af[mi] = *(const bf16x8*)((const char*)lds + off);
      }
#pragma unroll
      for (int ni = 0; ni < 4; ++ni) {
        int off = 8192 + (wc * 64 + ni * 16 + r15) * 128 + ((((ks * 4) + kblk) ^ swz) << 4);
        bfr[ni] = *(const bf16x8*)((const char*)lds + off);
      }
#pragma unroll
      for (int mi = 0; mi < 2; ++mi)
#pragma unroll
        for (int ni = 0; ni < 4; ++ni)
          acc[mi][ni] = __builtin_amdgcn_mfma_f32_16x16x32_bf16(af[mi], bfr[ni], acc[mi][ni], 0, 0, 0);
    }
    __syncthreads();
  }

  // epilogue: scale by x0[row, a], atomic-accumulate into out
  int jrow = (lane >> 4) * 4;
#pragma unroll
  for (int mi = 0; mi < 2; ++mi) {
#pragma unroll
    for (int j = 0; j < 4; ++j) {
      int row = n0 + wr * 32 + mi * 16 + jrow + j;
      float s = x0[(size_t)row * DIM0 + a];
#pragma unroll
      for (int ni = 0; ni < 4; ++ni) {
        int col = wc * 64 + ni * 16 + r15;
        atomicAdd(&out[(size_t)row * OO + col], acc[mi][ni][j] * s);
      }
    }
  }
}

// ---- bias + relu, in place on d_out ----
__global__ __launch_bounds__(256) void relu_kernel(float* __restrict__ out,
                                                   const float* __restrict__ bias) {
  int i = blockIdx.x * 256 + threadIdx.x;
  out[i] = fmaxf(out[i] + bias[i & (OO - 1)], 0.f);
}

extern "C" void kernel_launch(void* const* d_in, const int* in_sizes, int n_in,
                              void* d_out, int out_size, void* d_ws, size_t ws_size,
                              hipStream_t stream) {
  const float* x0   = (const float*)d_in[0];
  const float* x1   = (const float*)d_in[1];
  const float* x2   = (const float*)d_in[2];
  const float* W    = (const float*)d_in[3];
  const float* bias = (const float*)d_in[4];
  float* out = (float*)d_out;

  ushort* U  = (ushort*)d_ws;                                   // 2048*2176*2 = 8,912,896 B
  ushort* Wt = (ushort*)((char*)d_ws + (size_t)8912896);        // 33*128*2176*2 = 18,382,848 B

  hipMemsetAsync(d_out, 0, (size_t)NROW * OO * sizeof(float), stream);
  prep_u_kernel<<<NROW, 256, 0, stream>>>(x1, x2, U);
  prep_wt_kernel<<<dim3(34, 33), 256, 0, stream>>>(W, Wt);
  gemm_kernel<<<1056, 256, 0, stream>>>(U, Wt, x0, out);
  relu_kernel<<<(NROW * OO) / 256, 256, 0, stream>>>(out, bias);
}

// Round 3
// 114.307 us; speedup vs baseline: 1.3045x; 1.0487x over previous
//
#include <hip/hip_runtime.h>
#include <hip/hip_bf16.h>

typedef __attribute__((ext_vector_type(8))) short bf16x8;
typedef __attribute__((ext_vector_type(4))) float f32x4;

#define U_LD 2176      // padded K (multiple of 64)
#define K_REAL 2145    // 33*65
#define NKT 34         // 2176/64
#define DIM0 33
#define DIM1 33
#define DIM2 65
#define NROW 2048
#define OO 128

__device__ __forceinline__ unsigned short f2bf(float f) {
  union { float f; unsigned u; } v; v.f = f;
  unsigned r = v.u + 0x7fffu + ((v.u >> 16) & 1u);   // round-to-nearest-even
  return (unsigned short)(r >> 16);
}

#define GLOAD_LDS16(SRC, DST) \
  __builtin_amdgcn_global_load_lds((const __attribute__((address_space(1))) void*)(SRC), \
                                   (__attribute__((address_space(3))) void*)(DST), 16, 0, 0)

// ---- U[n][k] = bf16( x1[n,b] * x2[n,c] ),  k = b*65+c, zero-padded to 2176 ----
__global__ __launch_bounds__(256) void prep_u_kernel(const float* __restrict__ x1,
                                                     const float* __restrict__ x2,
                                                     ushort* __restrict__ U) {
  __shared__ float s1[DIM1], s2[DIM2];
  int n = blockIdx.x;
  int tid = threadIdx.x;
  if (tid < DIM1) s1[tid] = x1[n * DIM1 + tid];
  int t2 = tid - DIM1;
  if (t2 >= 0 && t2 < DIM2) s2[t2] = x2[n * DIM2 + t2];
  __syncthreads();
  for (int k8 = tid; k8 < U_LD / 8; k8 += 256) {
    union { ushort us[8]; uint4 v; } pk;
#pragma unroll
    for (int j = 0; j < 8; ++j) {
      int k = k8 * 8 + j;
      float val = 0.f;
      if (k < K_REAL) { int b = k / DIM2; int c = k - b * DIM2; val = s1[b] * s2[c]; }
      pk.us[j] = f2bf(val);
    }
    *(uint4*)&U[(size_t)n * U_LD + k8 * 8] = pk.v;
  }
}

// ---- Wt[a][o][k] = bf16( W[a,b,c,o] ), k = b*65+c, zero-padded ----
__global__ __launch_bounds__(256) void prep_wt_kernel(const float* __restrict__ W,
                                                      ushort* __restrict__ Wt) {
  __shared__ ushort s[64][130];   // [k][o], pad to 130 to spread banks
  int a = blockIdx.y;
  int k0 = blockIdx.x * 64;       // 34 slabs of 64 k
  int tid = threadIdx.x;
  for (int idx = tid; idx < 64 * 32; idx += 256) {
    int kk = idx >> 5;
    int og = (idx & 31) * 4;
    int k = k0 + kk;
    float4 v = make_float4(0.f, 0.f, 0.f, 0.f);
    if (k < K_REAL) {
      int b = k / DIM2; int c = k - b * DIM2;
      v = *(const float4*)&W[(((size_t)a * DIM1 + b) * DIM2 + c) * OO + og];
    }
    s[kk][og]     = f2bf(v.x);
    s[kk][og + 1] = f2bf(v.y);
    s[kk][og + 2] = f2bf(v.z);
    s[kk][og + 3] = f2bf(v.w);
  }
  __syncthreads();
  int o  = tid >> 1;
  int kh = (tid & 1) * 32;
  union { ushort us[32]; uint4 v[4]; } pk;
#pragma unroll
  for (int j = 0; j < 32; ++j) pk.us[j] = s[kh + j][o];
  uint4* dst = (uint4*)&Wt[((size_t)a * OO + o) * U_LD + k0 + kh];
#pragma unroll
  for (int q = 0; q < 4; ++q) dst[q] = pk.v[q];
}

// ---- main GEMM: per block (m-tile of 64 rows, one a): P = U_tile x Wt_a,
//      epilogue: out[n,o] += x0[n,a] * P[n,o]  (atomic) ----
// Double-buffered LDS, prefetch-before-compute, ONE barrier per K-step (T3 min-2ph).
__global__ __launch_bounds__(256) void gemm_kernel(const ushort* __restrict__ U,
                                                   const ushort* __restrict__ Wt,
                                                   const float* __restrict__ x0,
                                                   float* __restrict__ out) {
  // per buffer: A [64 rows][64 k] = 8KB (ushort 0..4095), B [128 o][64 k] = 16KB (4096..12287)
  __shared__ ushort lds[2][12288];   // 48 KB -> 3 blocks/CU

  int tid = threadIdx.x;
  int lane = tid & 63;
  int w = tid >> 6;
  int wr = w >> 1, wc = w & 1;

  // XCD-aware bijective swizzle: 1056 blocks, 1056/8 = 132 per XCD.
  int orig = (int)blockIdx.x;
  int logical = (orig & 7) * 132 + (orig >> 3);
  int a = logical >> 5;        // 0..32 (a-major: consecutive logical share Wt_a in L2)
  int m = logical & 31;        // 0..31
  int n0 = m * 64;

  int kblk = lane >> 4;        // 0..3
  int r15 = lane & 15;
  int swz = lane & 7;          // == row&7 for all fragment rows this lane touches

  f32x4 acc[2][4];
#pragma unroll
  for (int mi = 0; mi < 2; ++mi)
#pragma unroll
    for (int ni = 0; ni < 4; ++ni)
      acc[mi][ni] = (f32x4){0.f, 0.f, 0.f, 0.f};

  const ushort* WtA = Wt + (size_t)a * OO * U_LD;

  // stage K-step t into buffer buf (linear LDS dest, inverse-swizzled global source)
  auto STAGE = [&](int t, int buf) {
    int kk = t * 64;
#pragma unroll
    for (int i = 0; i < 2; ++i) {           // A: 512 x 16B chunks
      int c = i * 256 + tid;
      int row = c >> 3;
      int ss = (c & 7) ^ (row & 7);
      const ushort* src = U + (size_t)(n0 + row) * U_LD + kk + ss * 8;
      GLOAD_LDS16(src, &lds[buf][(size_t)c * 8]);
    }
#pragma unroll
    for (int i = 0; i < 4; ++i) {           // B: 1024 x 16B chunks
      int c = i * 256 + tid;
      int row = c >> 3;                     // o index
      int ss = (c & 7) ^ (row & 7);
      const ushort* src = WtA + (size_t)row * U_LD + kk + ss * 8;
      GLOAD_LDS16(src, &lds[buf][4096 + (size_t)c * 8]);
    }
  };

  auto COMPUTE = [&](int buf) {
    const char* base = (const char*)&lds[buf][0];
#pragma unroll
    for (int ks = 0; ks < 2; ++ks) {
      bf16x8 af[2], bfr[4];
#pragma unroll
      for (int mi = 0; mi < 2; ++mi) {
        int off = (wr * 32 + mi * 16 + r15) * 128 + ((((ks * 4) + kblk) ^ swz) << 4);
        af[mi] = *(const bf16x8*)(base + off);
      }
#pragma unroll
      for (int ni = 0; ni < 4; ++ni) {
        int off = 8192 + (wc * 64 + ni * 16 + r15) * 128 + ((((ks * 4) + kblk) ^ swz) << 4);
        bfr[ni] = *(const bf16x8*)(base + off);
      }
#pragma unroll
      for (int mi = 0; mi < 2; ++mi)
#pragma unroll
        for (int ni = 0; ni < 4; ++ni)
          acc[mi][ni] = __builtin_amdgcn_mfma_f32_16x16x32_bf16(af[mi], bfr[ni], acc[mi][ni], 0, 0, 0);
    }
  };

  // prologue
  STAGE(0, 0);
  __syncthreads();           // implicit vmcnt(0) drain: buf0 ready
  int cur = 0;
  // steady state: prefetch(t+1) overlaps compute(t); ONE barrier per K-step
  for (int t = 0; t < NKT - 1; ++t) {
    STAGE(t + 1, cur ^ 1);
    COMPUTE(cur);
    __syncthreads();         // drains vmcnt(0)+lgkmcnt(0): next buf ready, reads of cur done
    cur ^= 1;
  }
  COMPUTE(cur);              // last tile, no prefetch

  // epilogue: scale by x0[row, a], atomic-accumulate into out
  int jrow = (lane >> 4) * 4;
#pragma unroll
  for (int mi = 0; mi < 2; ++mi) {
#pragma unroll
    for (int j = 0; j < 4; ++j) {
      int row = n0 + wr * 32 + mi * 16 + jrow + j;
      float s = x0[(size_t)row * DIM0 + a];
#pragma unroll
      for (int ni = 0; ni < 4; ++ni) {
        int col = wc * 64 + ni * 16 + r15;
        atomicAdd(&out[(size_t)row * OO + col], acc[mi][ni][j] * s);
      }
    }
  }
}

// ---- bias + relu, in place on d_out ----
__global__ __launch_bounds__(256) void relu_kernel(float* __restrict__ out,
                                                   const float* __restrict__ bias) {
  int i = blockIdx.x * 256 + threadIdx.x;
  out[i] = fmaxf(out[i] + bias[i & (OO - 1)], 0.f);
}

extern "C" void kernel_launch(void* const* d_in, const int* in_sizes, int n_in,
                              void* d_out, int out_size, void* d_ws, size_t ws_size,
                              hipStream_t stream) {
  const float* x0   = (const float*)d_in[0];
  const float* x1   = (const float*)d_in[1];
  const float* x2   = (const float*)d_in[2];
  const float* W    = (const float*)d_in[3];
  const float* bias = (const float*)d_in[4];
  float* out = (float*)d_out;

  ushort* U  = (ushort*)d_ws;                                   // 2048*2176*2 = 8,912,896 B
  ushort* Wt = (ushort*)((char*)d_ws + (size_t)8912896);        // 33*128*2176*2 = 18,382,848 B

  hipMemsetAsync(d_out, 0, (size_t)NROW * OO * sizeof(float), stream);
  prep_u_kernel<<<NROW, 256, 0, stream>>>(x1, x2, U);
  prep_wt_kernel<<<dim3(34, 33), 256, 0, stream>>>(W, Wt);
  gemm_kernel<<<1056, 256, 0, stream>>>(U, Wt, x0, out);
  relu_kernel<<<(NROW * OO) / 256, 256, 0, stream>>>(out, bias);
}

// Round 4
// 102.471 us; speedup vs baseline: 1.4552x; 1.1155x over previous
//
#include <hip/hip_runtime.h>
#include <hip/hip_bf16.h>

typedef __attribute__((ext_vector_type(8))) short bf16x8;
typedef __attribute__((ext_vector_type(4))) float f32x4;

#define U_LD 2176      // padded K (multiple of 64)
#define K_REAL 2145    // 33*65
#define NKT 34         // 2176/64
#define DIM0 33
#define DIM1 33
#define DIM2 65
#define NROW 2048
#define OO 128

__device__ __forceinline__ unsigned short f2bf(float f) {
  union { float f; unsigned u; } v; v.f = f;
  unsigned r = v.u + 0x7fffu + ((v.u >> 16) & 1u);   // round-to-nearest-even
  return (unsigned short)(r >> 16);
}

#define GLOAD_LDS16(SRC, DST) \
  __builtin_amdgcn_global_load_lds((const __attribute__((address_space(1))) void*)(SRC), \
                                   (__attribute__((address_space(3))) void*)(DST), 16, 0, 0)

// ---- U[n][k] = bf16( x1[n,b] * x2[n,c] ),  k = b*65+c, zero-padded to 2176 ----
__global__ __launch_bounds__(256) void prep_u_kernel(const float* __restrict__ x1,
                                                     const float* __restrict__ x2,
                                                     ushort* __restrict__ U) {
  __shared__ float s1[DIM1], s2[DIM2];
  int n = blockIdx.x;
  int tid = threadIdx.x;
  if (tid < DIM1) s1[tid] = x1[n * DIM1 + tid];
  int t2 = tid - DIM1;
  if (t2 >= 0 && t2 < DIM2) s2[t2] = x2[n * DIM2 + t2];
  __syncthreads();
  for (int k8 = tid; k8 < U_LD / 8; k8 += 256) {
    union { ushort us[8]; uint4 v; } pk;
#pragma unroll
    for (int j = 0; j < 8; ++j) {
      int k = k8 * 8 + j;
      float val = 0.f;
      if (k < K_REAL) { int b = k / DIM2; int c = k - b * DIM2; val = s1[b] * s2[c]; }
      pk.us[j] = f2bf(val);
    }
    *(uint4*)&U[(size_t)n * U_LD + k8 * 8] = pk.v;
  }
}

// ---- Wt[a][o][k] = bf16( W[a,b,c,o] ), k = b*65+c, zero-padded ----
__global__ __launch_bounds__(256) void prep_wt_kernel(const float* __restrict__ W,
                                                      ushort* __restrict__ Wt) {
  __shared__ ushort s[64][130];   // [k][o], pad to 130 to spread banks
  int a = blockIdx.y;
  int k0 = blockIdx.x * 64;       // 34 slabs of 64 k
  int tid = threadIdx.x;
  for (int idx = tid; idx < 64 * 32; idx += 256) {
    int kk = idx >> 5;
    int og = (idx & 31) * 4;
    int k = k0 + kk;
    float4 v = make_float4(0.f, 0.f, 0.f, 0.f);
    if (k < K_REAL) {
      int b = k / DIM2; int c = k - b * DIM2;
      v = *(const float4*)&W[(((size_t)a * DIM1 + b) * DIM2 + c) * OO + og];
    }
    s[kk][og]     = f2bf(v.x);
    s[kk][og + 1] = f2bf(v.y);
    s[kk][og + 2] = f2bf(v.z);
    s[kk][og + 3] = f2bf(v.w);
  }
  __syncthreads();
  int o  = tid >> 1;
  int kh = (tid & 1) * 32;
  union { ushort us[32]; uint4 v[4]; } pk;
#pragma unroll
  for (int j = 0; j < 32; ++j) pk.us[j] = s[kh + j][o];
  uint4* dst = (uint4*)&Wt[((size_t)a * OO + o) * U_LD + k0 + kh];
#pragma unroll
  for (int q = 0; q < 4; ++q) dst[q] = pk.v[q];
}

// ---- main GEMM: 64x128 tile, one a per block; counted-vmcnt double-buffer pipeline.
//      T4: raw s_barrier + s_waitcnt vmcnt(6) -- next tile's 6 loads stay in flight
//      across barriers (never drain to 0 in the main loop).
__global__ __launch_bounds__(256) void gemm_kernel(const ushort* __restrict__ U,
                                                   const ushort* __restrict__ Wt,
                                                   const float* __restrict__ x0,
                                                   float* __restrict__ out) {
  // per buffer: A [64 rows][64 k] = 8KB (ushort 0..4095), B [128 o][64 k] = 16KB (4096..12287)
  __shared__ ushort lds[2][12288];   // 48 KB -> 3 blocks/CU

  int tid = threadIdx.x;
  int lane = tid & 63;
  int w = tid >> 6;
  int wr = w >> 1, wc = w & 1;

  // XCD-aware bijective swizzle: 1056 blocks, 132 per XCD, a-major within XCD.
  int orig = (int)blockIdx.x;
  int logical = (orig & 7) * 132 + (orig >> 3);
  int a = logical >> 5;        // 0..32
  int m = logical & 31;        // 0..31
  int n0 = m * 64;

  int kblk = lane >> 4;        // 0..3
  int r15 = lane & 15;
  int swz = lane & 7;

  f32x4 acc[2][4];
#pragma unroll
  for (int mi = 0; mi < 2; ++mi)
#pragma unroll
    for (int ni = 0; ni < 4; ++ni)
      acc[mi][ni] = (f32x4){0.f, 0.f, 0.f, 0.f};

  const ushort* WtA = Wt + (size_t)a * OO * U_LD;

  // --- per-thread staging constants: 6 chunks, pointer-bumped (+64 ushorts/step) ---
  int c0 = tid;        int rA0 = c0 >> 3;  int dA0 = c0 * 8;
  int c1 = 256 + tid;  int rA1 = c1 >> 3;  int dA1 = c1 * 8;
  const ushort* pA0 = U + (size_t)(n0 + rA0) * U_LD + ((c0 & 7) ^ (rA0 & 7)) * 8;
  const ushort* pA1 = U + (size_t)(n0 + rA1) * U_LD + ((c1 & 7) ^ (rA1 & 7)) * 8;
  int cB0 = tid;        int rB0 = cB0 >> 3;  int dB0 = 4096 + cB0 * 8;
  int cB1 = 256 + tid;  int rB1 = cB1 >> 3;  int dB1 = 4096 + cB1 * 8;
  int cB2 = 512 + tid;  int rB2 = cB2 >> 3;  int dB2 = 4096 + cB2 * 8;
  int cB3 = 768 + tid;  int rB3 = cB3 >> 3;  int dB3 = 4096 + cB3 * 8;
  const ushort* pB0 = WtA + (size_t)rB0 * U_LD + ((cB0 & 7) ^ (rB0 & 7)) * 8;
  const ushort* pB1 = WtA + (size_t)rB1 * U_LD + ((cB1 & 7) ^ (rB1 & 7)) * 8;
  const ushort* pB2 = WtA + (size_t)rB2 * U_LD + ((cB2 & 7) ^ (rB2 & 7)) * 8;
  const ushort* pB3 = WtA + (size_t)rB3 * U_LD + ((cB3 & 7) ^ (rB3 & 7)) * 8;

  auto STAGE = [&](ushort* Lb) {
    GLOAD_LDS16(pA0, Lb + dA0); pA0 += 64;
    GLOAD_LDS16(pA1, Lb + dA1); pA1 += 64;
    GLOAD_LDS16(pB0, Lb + dB0); pB0 += 64;
    GLOAD_LDS16(pB1, Lb + dB1); pB1 += 64;
    GLOAD_LDS16(pB2, Lb + dB2); pB2 += 64;
    GLOAD_LDS16(pB3, Lb + dB3); pB3 += 64;
  };

  auto COMPUTE = [&](const ushort* Lb) {
    const char* base = (const char*)Lb;
#pragma unroll
    for (int ks = 0; ks < 2; ++ks) {
      bf16x8 af[2], bfr[4];
#pragma unroll
      for (int mi = 0; mi < 2; ++mi) {
        int off = (wr * 32 + mi * 16 + r15) * 128 + ((((ks * 4) + kblk) ^ swz) << 4);
        af[mi] = *(const bf16x8*)(base + off);
      }
#pragma unroll
      for (int ni = 0; ni < 4; ++ni) {
        int off = 8192 + (wc * 64 + ni * 16 + r15) * 128 + ((((ks * 4) + kblk) ^ swz) << 4);
        bfr[ni] = *(const bf16x8*)(base + off);
      }
      __builtin_amdgcn_s_setprio(1);
#pragma unroll
      for (int mi = 0; mi < 2; ++mi)
#pragma unroll
        for (int ni = 0; ni < 4; ++ni)
          acc[mi][ni] = __builtin_amdgcn_mfma_f32_16x16x32_bf16(af[mi], bfr[ni], acc[mi][ni], 0, 0, 0);
      __builtin_amdgcn_s_setprio(0);
    }
  };

  // prologue: tiles 0,1 in flight; wait only for tile 0 (6 of 12 loads)
  STAGE(&lds[0][0]);
  STAGE(&lds[1][0]);
  asm volatile("s_waitcnt vmcnt(6)" ::: "memory");
  __builtin_amdgcn_s_barrier();

  // steady state: tiles 0..31; buffer index compile-time via 2x unroll.
  // Invariant at each COMPUTE: that buffer's tile landed; other buffer's 6 loads in flight.
  for (int it = 0; it < 16; ++it) {
    COMPUTE(&lds[0][0]);
    __builtin_amdgcn_s_barrier();            // readers done with b0 (no drain)
    STAGE(&lds[0][0]);                       // tile 2it+2 -> b0 (12 in flight)
    asm volatile("s_waitcnt vmcnt(6)" ::: "memory");   // b1's tile landed
    __builtin_amdgcn_s_barrier();
    COMPUTE(&lds[1][0]);
    __builtin_amdgcn_s_barrier();
    STAGE(&lds[1][0]);                       // tile 2it+3 -> b1
    asm volatile("s_waitcnt vmcnt(6)" ::: "memory");   // b0's tile landed
    __builtin_amdgcn_s_barrier();
  }
  // tiles 32 (b0, landed) and 33 (b1, in flight)
  COMPUTE(&lds[0][0]);
  asm volatile("s_waitcnt vmcnt(0)" ::: "memory");
  __builtin_amdgcn_s_barrier();
  COMPUTE(&lds[1][0]);

  // epilogue: scale by x0[row, a], atomic-accumulate into out
  int jrow = (lane >> 4) * 4;
#pragma unroll
  for (int mi = 0; mi < 2; ++mi) {
#pragma unroll
    for (int j = 0; j < 4; ++j) {
      int row = n0 + wr * 32 + mi * 16 + jrow + j;
      float s = x0[(size_t)row * DIM0 + a];
#pragma unroll
      for (int ni = 0; ni < 4; ++ni) {
        int col = wc * 64 + ni * 16 + r15;
        atomicAdd(&out[(size_t)row * OO + col], acc[mi][ni][j] * s);
      }
    }
  }
}

// ---- bias + relu, in place on d_out ----
__global__ __launch_bounds__(256) void relu_kernel(float* __restrict__ out,
                                                   const float* __restrict__ bias) {
  int i = blockIdx.x * 256 + threadIdx.x;
  out[i] = fmaxf(out[i] + bias[i & (OO - 1)], 0.f);
}

extern "C" void kernel_launch(void* const* d_in, const int* in_sizes, int n_in,
                              void* d_out, int out_size, void* d_ws, size_t ws_size,
                              hipStream_t stream) {
  const float* x0   = (const float*)d_in[0];
  const float* x1   = (const float*)d_in[1];
  const float* x2   = (const float*)d_in[2];
  const float* W    = (const float*)d_in[3];
  const float* bias = (const float*)d_in[4];
  float* out = (float*)d_out;

  ushort* U  = (ushort*)d_ws;                                   // 2048*2176*2 = 8,912,896 B
  ushort* Wt = (ushort*)((char*)d_ws + (size_t)8912896);        // 33*128*2176*2 = 18,382,848 B

  hipMemsetAsync(d_out, 0, (size_t)NROW * OO * sizeof(float), stream);
  prep_u_kernel<<<NROW, 256, 0, stream>>>(x1, x2, U);
  prep_wt_kernel<<<dim3(34, 33), 256, 0, stream>>>(W, Wt);
  gemm_kernel<<<1056, 256, 0, stream>>>(U, Wt, x0, out);
  relu_kernel<<<(NROW * OO) / 256, 256, 0, stream>>>(out, bias);
}